// Round 1
// baseline (316.644 us; speedup 1.0000x reference)
//
#include <hip/hip_runtime.h>
#include <math.h>

#define B_   2
#define S_   2048
#define HID_ 1024
#define D_   64
#define H_   16
#define ROT_ 32
#define M_   (B_*S_)

typedef __attribute__((ext_vector_type(4))) short  short4v;
typedef __attribute__((ext_vector_type(8))) short  short8;
typedef __attribute__((ext_vector_type(4))) float  floatx4;
typedef __attribute__((ext_vector_type(16))) float floatx16;
typedef __attribute__((ext_vector_type(2))) unsigned int uint2v;

__device__ __forceinline__ unsigned short f2bf(float f) {
  unsigned int x = __builtin_bit_cast(unsigned int, f);
  x += 0x7fffu + ((x >> 16) & 1u);   // RNE; inputs finite
  return (unsigned short)(x >> 16);
}
__device__ __forceinline__ unsigned int cvt_pk_bf16(float lo, float hi) {
  unsigned int r;
  asm("v_cvt_pk_bf16_f32 %0, %1, %2" : "=v"(r) : "v"(lo), "v"(hi));
  return r;
}
// async global->LDS, 16B per lane; lds dest = wave-uniform base + lane*16
__device__ __forceinline__ void gload_lds16(const unsigned short* g, unsigned short* l) {
  __builtin_amdgcn_global_load_lds(
      (const __attribute__((address_space(1))) unsigned int*)g,
      (__attribute__((address_space(3))) unsigned int*)l, 16, 0, 0);
}

// ---------------- cast x (fp32 -> bf16) ----------------
__global__ void cast_bf16(const float* __restrict__ in, unsigned short* __restrict__ out) {
  int i = (blockIdx.x * 256 + threadIdx.x) * 4;
  floatx4 v = *(const floatx4*)(in + i);
  unsigned short o[4];
  o[0] = f2bf(v[0]); o[1] = f2bf(v[1]); o[2] = f2bf(v[2]); o[3] = f2bf(v[3]);
  *(unsigned long long*)(out + i) = *(unsigned long long*)o;
}

// ------------- transpose + cast weights: T[n][k] = bf16(W[k][n]) -------------
__global__ void transW(const float* __restrict__ W0, const float* __restrict__ W1,
                       const float* __restrict__ W2, const float* __restrict__ W3,
                       unsigned short* __restrict__ T0, unsigned short* __restrict__ T1,
                       unsigned short* __restrict__ T2, unsigned short* __restrict__ T3) {
  const float* W; unsigned short* T;
  int z = blockIdx.z;
  if (z == 0)      { W = W0; T = T0; }
  else if (z == 1) { W = W1; T = T1; }
  else if (z == 2) { W = W2; T = T2; }
  else             { W = W3; T = T3; }
  __shared__ float tile[32][33];
  int bx = blockIdx.x * 32, by = blockIdx.y * 32;
  int tx = threadIdx.x, ty = threadIdx.y;
  #pragma unroll
  for (int j = 0; j < 4; j++)
    tile[ty + j*8][tx] = W[(size_t)(by + ty + j*8) * HID_ + bx + tx];
  __syncthreads();
  #pragma unroll
  for (int j = 0; j < 4; j++)
    T[(size_t)(bx + ty + j*8) * HID_ + by + tx] = f2bf(tile[tx][ty + j*8]);
}

// ---------------- GEMM: C[M,N] = A[M,K] @ Bt[N,K]^T (+bias) ----------------
// MODE 0: QKV producer. z=0: Q bf16, rope + scale c1. z=1: K bf16, rope.
//         z=2: V bf16 written TRANSPOSED into Vt[b][h][d][s].
template <int MODE>
__global__ __launch_bounds__(256) void gemm_bt(
    const unsigned short* __restrict__ A,
    const unsigned short* __restrict__ Bt0, const unsigned short* __restrict__ Bt1,
    const unsigned short* __restrict__ Bt2,
    const float* __restrict__ bias0, const float* __restrict__ bias1,
    const float* __restrict__ bias2,
    void* __restrict__ out0, void* __restrict__ out1, void* __restrict__ out2,
    const float* __restrict__ sins, float sc0)
{
  const unsigned short* Bt; const float* bias; void* Out; float sc;
  if (blockIdx.z == 0)      { Bt = Bt0; bias = bias0; Out = out0; sc = sc0; }
  else if (blockIdx.z == 1) { Bt = Bt1; bias = bias1; Out = out1; sc = 1.f; }
  else                      { Bt = Bt2; bias = bias2; Out = out2; sc = 1.f; }
  const int K = HID_, N = HID_;
  int m0 = blockIdx.y * 128, n0 = blockIdx.x * 128;
  __shared__ alignas(16) unsigned short sA[128 * 32];
  __shared__ alignas(16) unsigned short sB[128 * 32];
  int t = threadIdx.x;
  int lane = t & 63, wave = t >> 6;
  int quad = lane >> 4, l16 = lane & 15;
  int wr = wave >> 1, wc = wave & 1;

  int srow = (lane >> 2), scol = (lane & 3) * 8;
  const unsigned short* gA0 = A  + (size_t)(m0 + wave*32 +  0 + srow) * K + scol;
  const unsigned short* gA1 = A  + (size_t)(m0 + wave*32 + 16 + srow) * K + scol;
  const unsigned short* gB0 = Bt + (size_t)(n0 + wave*32 +  0 + srow) * K + scol;
  const unsigned short* gB1 = Bt + (size_t)(n0 + wave*32 + 16 + srow) * K + scol;
  unsigned short* lA0 = sA + (wave*32 +  0) * 32;
  unsigned short* lA1 = sA + (wave*32 + 16) * 32;
  unsigned short* lB0 = sB + (wave*32 +  0) * 32;
  unsigned short* lB1 = sB + (wave*32 + 16) * 32;

  floatx4 acc[4][4];
  #pragma unroll
  for (int i = 0; i < 4; i++)
    #pragma unroll
    for (int j = 0; j < 4; j++)
      acc[i][j] = (floatx4){0.f, 0.f, 0.f, 0.f};

  for (int k0 = 0; k0 < K; k0 += 32) {
    gload_lds16(gA0 + k0, lA0);
    gload_lds16(gA1 + k0, lA1);
    gload_lds16(gB0 + k0, lB0);
    gload_lds16(gB1 + k0, lB1);
    __syncthreads();
    short8 af[4], bf[4];
    #pragma unroll
    for (int i = 0; i < 4; i++) {
      af[i] = *(const short8*)(sA + (wr * 64 + i * 16 + l16) * 32 + quad * 8);
      bf[i] = *(const short8*)(sB + (wc * 64 + i * 16 + l16) * 32 + quad * 8);
    }
    #pragma unroll
    for (int i = 0; i < 4; i++)
      #pragma unroll
      for (int j = 0; j < 4; j++)
        acc[i][j] = __builtin_amdgcn_mfma_f32_16x16x32_bf16(af[i], bf[j], acc[i][j], 0, 0, 0);
    __syncthreads();
  }

  // Epilogue. C/D layout: col = lane&15, row = quad*4 + reg.
  #pragma unroll
  for (int i = 0; i < 4; i++) {
    int mbase = m0 + wr * 64 + i * 16 + quad * 4;
    #pragma unroll
    for (int j = 0; j < 4; j++) {
      int n = n0 + wc * 64 + j * 16 + l16;
      float bv = bias ? bias[n] : 0.f;
      if (MODE == 1) {
        #pragma unroll
        for (int r = 0; r < 4; r++)
          ((float*)Out)[(size_t)(mbase + r) * N + n] = acc[i][j][r] + bv;
      } else if (blockIdx.z == 2) {
        // V: write transposed Vt[((b*16+h)*64+dd)*2048 + s], 4 consecutive s packed
        int bb = mbase >> 11, ss = mbase & 2047;
        int hh = n >> 6, dd = n & 63;
        unsigned short pk[4];
        #pragma unroll
        for (int r = 0; r < 4; r++) pk[r] = f2bf(acc[i][j][r] + bv);
        *(unsigned long long*)((unsigned short*)Out +
            (((size_t)(bb * H_ + hh) * D_ + dd) * S_ + ss)) = *(unsigned long long*)pk;
      } else if (j < 2) {
        // rope columns: head-dim index jh = j*16 + l16 < 32 (wave-uniform branch)
        int jh = j * 16 + l16;
        #pragma unroll
        for (int r = 0; r < 4; r++) {
          int row = mbase + r, bb = row >> 11, ss = row & 2047;
          float sn = sins[((size_t)(bb * 2 + 0) * S_ + ss) * ROT_ + jh];
          float cs = sins[((size_t)(bb * 2 + 1) * S_ + ss) * ROT_ + jh];
          float f = (jh & 1) ? (cs + sn) : (cs - sn);
          ((unsigned short*)Out)[(size_t)row * N + n] = f2bf((acc[i][j][r] + bv) * f * sc);
        }
      } else {
        #pragma unroll
        for (int r = 0; r < 4; r++)
          ((unsigned short*)Out)[(size_t)(mbase + r) * N + n] = f2bf((acc[i][j][r] + bv) * sc);
      }
    }
  }
}

// ---- final projection GEMM: 128(M)x64(N) tile, fp32 out, 512 blocks (2/CU) ----
__global__ __launch_bounds__(256) void gemm_bt64(
    const unsigned short* __restrict__ A, const unsigned short* __restrict__ Bt,
    float* __restrict__ Out)
{
  const int K = HID_, N = HID_;
  int m0 = blockIdx.y * 128, n0 = blockIdx.x * 64;
  __shared__ alignas(16) unsigned short sA[128 * 32];
  __shared__ alignas(16) unsigned short sB[64 * 32];
  int t = threadIdx.x;
  int lane = t & 63, wave = t >> 6;
  int quad = lane >> 4, l16 = lane & 15;
  int wr = wave >> 1, wc = wave & 1;   // per-wave 64(M) x 32(N)

  int srow = lane >> 2, scol = (lane & 3) * 8;
  const unsigned short* gA0 = A  + (size_t)(m0 + wave*32 +  0 + srow) * K + scol;
  const unsigned short* gA1 = A  + (size_t)(m0 + wave*32 + 16 + srow) * K + scol;
  const unsigned short* gB0 = Bt + (size_t)(n0 + wave*16 + srow) * K + scol;
  unsigned short* lA0 = sA + (wave*32 +  0) * 32;
  unsigned short* lA1 = sA + (wave*32 + 16) * 32;
  unsigned short* lB0 = sB + (wave*16) * 32;

  floatx4 acc[4][2];
  #pragma unroll
  for (int i = 0; i < 4; i++)
    #pragma unroll
    for (int j = 0; j < 2; j++)
      acc[i][j] = (floatx4){0.f, 0.f, 0.f, 0.f};

  for (int k0 = 0; k0 < K; k0 += 32) {
    gload_lds16(gA0 + k0, lA0);
    gload_lds16(gA1 + k0, lA1);
    gload_lds16(gB0 + k0, lB0);
    __syncthreads();
    short8 af[4], bf[2];
    #pragma unroll
    for (int i = 0; i < 4; i++)
      af[i] = *(const short8*)(sA + (wr * 64 + i * 16 + l16) * 32 + quad * 8);
    #pragma unroll
    for (int j = 0; j < 2; j++)
      bf[j] = *(const short8*)(sB + (wc * 32 + j * 16 + l16) * 32 + quad * 8);
    #pragma unroll
    for (int i = 0; i < 4; i++)
      #pragma unroll
      for (int j = 0; j < 2; j++)
        acc[i][j] = __builtin_amdgcn_mfma_f32_16x16x32_bf16(af[i], bf[j], acc[i][j], 0, 0, 0);
    __syncthreads();
  }

  #pragma unroll
  for (int i = 0; i < 4; i++) {
    int mbase = m0 + wr * 64 + i * 16 + quad * 4;
    #pragma unroll
    for (int j = 0; j < 2; j++) {
      int n = n0 + wc * 32 + j * 16 + l16;
      #pragma unroll
      for (int r = 0; r < 4; r++)
        Out[(size_t)(mbase + r) * N + n] = acc[i][j][r];
    }
  }
}

// ---------------- flash attention: S^T trick + in-block split-K ----------------
// 8 waves: group g = wave>>2 handles k-half [g*1024, (g+1)*1024) for the SAME
// 128 q-rows (wave wg = wave&3 owns 32 q). Fixed-max exp2 softmax -> partial
// (O,l) of the two halves combine by pure addition via a 32KB LDS exchange.
// 512 blocks x 8 waves = 16 waves/CU (2 blocks/CU: LDS 73728B, VGPR<=128).
__global__ __launch_bounds__(512, 4) void attn(
    const unsigned short* __restrict__ Q, const unsigned short* __restrict__ Kb,
    const unsigned short* __restrict__ Vt, const float* __restrict__ bias,
    unsigned short* __restrict__ Out)
{
  int b = blockIdx.z, h = blockIdx.y;
  int t = threadIdx.x;
  int lane = t & 63, wave = t >> 6;
  int g = wave >> 2, wg = wave & 3;
  int l32 = lane & 31, hl = lane >> 5;
  int q0 = blockIdx.x * 128 + wg * 32;
  const int RS = H_ * D_;
  const int NT = S_ / 128;   // 16 tiles of 64 keys per k-half

  // per group g: [Kbuf0][Kbuf1][Vbuf0][Vbuf1], each 64*72 shorts (pad 72)
  __shared__ alignas(16) unsigned short smem[2 * 18432];
  unsigned short* sKg = smem + g * 18432;
  unsigned short* sVg = sKg + 9216;

  const unsigned short* Qbase = Q + ((size_t)(b * S_) * H_ + h) * D_;
  const unsigned short* Kbase = Kb + ((size_t)(b * S_) * H_ + h) * D_;
  const unsigned short* Vbase = Vt + ((size_t)(b * H_) + h) * D_ * S_;

  // Q B-frags (n=q=lane&31, k=d=16s+8hl+j), fixed for whole kernel
  short8 qf[4];
  {
    const unsigned short* qp = Qbase + (size_t)(q0 + l32) * RS + 8 * hl;
    qf[0] = *(const short8*)(qp);
    qf[1] = *(const short8*)(qp + 16);
    qf[2] = *(const short8*)(qp + 32);
    qf[3] = *(const short8*)(qp + 48);
  }

  // staging: group-local thread tg -> row tg>>2, quarter tg&3, 2x16B chunks
  int tg = t & 255;
  int srow = tg >> 2, sq = tg & 3;
  const unsigned short* gK = Kbase + (size_t)(g * 1024 + srow) * RS + sq * 16;
  const unsigned short* gV = Vbase + (size_t)srow * S_ + g * 1024 + sq * 16;
  const int wOff = srow * 72 + sq * 16;

  const float* bp = bias + (size_t)b * S_ * S_ + (size_t)(q0 + l32) * S_ + g * 1024 + 4 * hl;

  float l_run = 0.f;
  floatx16 o0, o1;
  #pragma unroll
  for (int r = 0; r < 16; r++) { o0[r] = 0.f; o1[r] = 0.f; }

  // tile 0 of this half -> LDS buf 0; prefetch tile 1 into regs
  floatx4 kp[2], vp[2];
  kp[0] = *(const floatx4*)(gK);     kp[1] = *(const floatx4*)(gK + 8);
  vp[0] = *(const floatx4*)(gV);     vp[1] = *(const floatx4*)(gV + 8);
  *(floatx4*)(sKg + wOff)     = kp[0];
  *(floatx4*)(sKg + wOff + 8) = kp[1];
  *(floatx4*)(sVg + wOff)     = vp[0];
  *(floatx4*)(sVg + wOff + 8) = vp[1];
  kp[0] = *(const floatx4*)(gK + (size_t)64 * RS);
  kp[1] = *(const floatx4*)(gK + (size_t)64 * RS + 8);
  vp[0] = *(const floatx4*)(gV + 64);
  vp[1] = *(const floatx4*)(gV + 64 + 8);

  for (int it = 0; it < NT; ++it) {
    int cur = it & 1, nxt = cur ^ 1;
    __syncthreads();

    if (it < NT - 1) {
      *(floatx4*)(sKg + nxt * 4608 + wOff)     = kp[0];
      *(floatx4*)(sKg + nxt * 4608 + wOff + 8) = kp[1];
      *(floatx4*)(sVg + nxt * 4608 + wOff)     = vp[0];
      *(floatx4*)(sVg + nxt * 4608 + wOff + 8) = vp[1];
    }
    {
      int k2 = ((it + 2) & (NT - 1)) * 64;
      kp[0] = *(const floatx4*)(gK + (size_t)k2 * RS);
      kp[1] = *(const floatx4*)(gK + (size_t)k2 * RS + 8);
      vp[0] = *(const floatx4*)(gV + k2);
      vp[1] = *(const floatx4*)(gV + k2 + 8);
    }

    // bias loads early (independent of LDS)
    floatx4 bl[8];
    #pragma unroll
    for (int cc = 0; cc < 2; cc++)
      #pragma unroll
      for (int rg = 0; rg < 4; rg++)
        bl[cc * 4 + rg] = *(const floatx4*)(bp + it * 64 + cc * 32 + 8 * rg);

    const unsigned short* sKc = sKg + cur * 4608;
    const unsigned short* sVc = sVg + cur * 4608;

    // S^T: D[m=k][n=q], M-blocks cc over 64 k, K-steps over d=64
    floatx16 st[2];
    __builtin_amdgcn_s_setprio(1);
    #pragma unroll
    for (int cc = 0; cc < 2; cc++) {
      floatx16 s;
      #pragma unroll
      for (int r = 0; r < 16; r++) s[r] = 0.f;
      #pragma unroll
      for (int ks = 0; ks < 4; ks++) {
        short8 kf = *(const short8*)(sKc + (cc * 32 + l32) * 72 + 16 * ks + 8 * hl);
        s = __builtin_amdgcn_mfma_f32_32x32x16_bf16(kf, qf[ks], s, 0, 0, 0);
      }
      st[cc] = s;
    }
    __builtin_amdgcn_s_setprio(0);

    // p = exp2(s); l += p; pack p*bias into 32x32x8 A-frags (k=4hl+j == C-layout)
    short4v pf[2][4];
    #pragma unroll
    for (int cc = 0; cc < 2; cc++)
      #pragma unroll
      for (int rg = 0; rg < 4; rg++) {
        float p0 = __builtin_amdgcn_exp2f(st[cc][rg * 4 + 0]);
        float p1 = __builtin_amdgcn_exp2f(st[cc][rg * 4 + 1]);
        float p2 = __builtin_amdgcn_exp2f(st[cc][rg * 4 + 2]);
        float p3 = __builtin_amdgcn_exp2f(st[cc][rg * 4 + 3]);
        l_run += (p0 + p1) + (p2 + p3);
        uint2v u;
        u[0] = cvt_pk_bf16(p0 * bl[cc * 4 + rg][0], p1 * bl[cc * 4 + rg][1]);
        u[1] = cvt_pk_bf16(p2 * bl[cc * 4 + rg][2], p3 * bl[cc * 4 + rg][3]);
        pf[cc][rg] = __builtin_bit_cast(short4v, u);
      }

    // O += P @ V : 32x32x8, A=pf (regs), B=V[k][d] from sV[d][k]
    __builtin_amdgcn_s_setprio(1);
    #pragma unroll
    for (int cc = 0; cc < 2; cc++)
      #pragma unroll
      for (int gg = 0; gg < 4; gg++) {
        int kcol = cc * 32 + 8 * gg + 4 * hl;
        short4v vf0 = *(const short4v*)(sVc + (l32)      * 72 + kcol);
        short4v vf1 = *(const short4v*)(sVc + (32 + l32) * 72 + kcol);
        o0 = __builtin_amdgcn_mfma_f32_32x32x8bf16_1k(pf[cc][gg], vf0, o0, 0, 0, 0);
        o1 = __builtin_amdgcn_mfma_f32_32x32x8bf16_1k(pf[cc][gg], vf1, o1, 0, 0, 0);
      }
    __builtin_amdgcn_s_setprio(0);
  }

  // full k-half denominator for q-row l32 (partner half-lane has the other half)
  float l2 = l_run + __shfl_xor(l_run, 32);

  // combine the two k-halves through group-1's LDS region (done with its K/V)
  float* sO = (float*)(smem + 18432);   // 128 q x 64 d fp32 = 32KB
  float* sL = sO + 128 * 64;            // 128 floats

  __syncthreads();
  if (g == 1) {
    #pragma unroll
    for (int r = 0; r < 16; r++) {
      int ql = (r & 3) + 8 * (r >> 2) + 4 * hl;
      sO[(wg * 32 + ql) * 64 + l32]      = o0[r];
      sO[(wg * 32 + ql) * 64 + 32 + l32] = o1[r];
    }
    if (hl == 0) sL[wg * 32 + l32] = l2;
  }
  __syncthreads();
  if (g == 0) {
    float linv = __builtin_amdgcn_rcpf(l2 + sL[wg * 32 + l32]);
    #pragma unroll
    for (int r = 0; r < 16; r++) {
      int ql = (r & 3) + 8 * (r >> 2) + 4 * hl;
      float sc = __shfl(linv, ql);
      size_t base = ((size_t)(b * S_ + q0 + ql) * H_ + h) * D_;
      float a0 = o0[r] + sO[(wg * 32 + ql) * 64 + l32];
      float a1 = o1[r] + sO[(wg * 32 + ql) * 64 + 32 + l32];
      Out[base + l32]      = f2bf(a0 * sc);
      Out[base + 32 + l32] = f2bf(a1 * sc);
    }
  }
}

// ---------------- launch ----------------
extern "C" void kernel_launch(void* const* d_in, const int* in_sizes, int n_in,
                              void* d_out, int out_size, void* d_ws, size_t ws_size,
                              hipStream_t stream) {
  (void)in_sizes; (void)n_in; (void)out_size; (void)ws_size;
  const float* x    = (const float*)d_in[0];
  const float* sins = (const float*)d_in[1];
  const float* ab   = (const float*)d_in[2];
  const float* Wq   = (const float*)d_in[3];
  const float* bq   = (const float*)d_in[4];
  const float* Wk   = (const float*)d_in[5];
  const float* bk   = (const float*)d_in[6];
  const float* Wv   = (const float*)d_in[7];
  const float* bv   = (const float*)d_in[8];
  const float* Wo   = (const float*)d_in[9];
  float* out = (float*)d_out;
  char* ws = (char*)d_ws;

  unsigned short* xb  = (unsigned short*)(ws);                       // 8 MB
  unsigned short* Wqt = (unsigned short*)(ws + ((size_t) 8 << 20));  // 2 MB each
  unsigned short* Wkt = (unsigned short*)(ws + ((size_t)10 << 20));
  unsigned short* Wvt = (unsigned short*)(ws + ((size_t)12 << 20));
  unsigned short* Wot = (unsigned short*)(ws + ((size_t)14 << 20));
  unsigned short* Qb  = (unsigned short*)(ws + ((size_t)16 << 20));  // 8 MB
  unsigned short* Kb  = (unsigned short*)(ws + ((size_t)24 << 20));  // 8 MB
  unsigned short* Vtb = (unsigned short*)(ws + ((size_t)32 << 20));  // 8 MB, [b][h][d][s]
  unsigned short* Ab  = (unsigned short*)(ws + ((size_t)40 << 20));  // 8 MB

  const float c1 = 0.125f * 1.44269504088896f;  // 1/sqrt(D) * log2(e), folded into Q

  cast_bf16<<<dim3((M_ * HID_) / (256 * 4)), dim3(256), 0, stream>>>(x, xb);
  transW<<<dim3(32, 32, 4), dim3(32, 8), 0, stream>>>(Wq, Wk, Wv, Wo, Wqt, Wkt, Wvt, Wot);
  gemm_bt<0><<<dim3(8, 32, 3), dim3(256), 0, stream>>>(xb, Wqt, Wkt, Wvt, bq, bk, bv,
                                                       Qb, Kb, Vtb, sins, c1);
  attn<<<dim3(S_ / 128, H_, B_), dim3(512), 0, stream>>>(Qb, Kb, Vtb, ab, Ab);
  gemm_bt64<<<dim3(HID_ / 64, M_ / 128), dim3(256), 0, stream>>>(Ab, Wot, out);
}

// Round 2
// 284.885 us; speedup vs baseline: 1.1115x; 1.1115x over previous
//
#include <hip/hip_runtime.h>
#include <math.h>

#define B_   2
#define S_   2048
#define HID_ 1024
#define D_   64
#define H_   16
#define ROT_ 32
#define M_   (B_*S_)

typedef __attribute__((ext_vector_type(4))) short  short4v;
typedef __attribute__((ext_vector_type(8))) short  short8;
typedef __attribute__((ext_vector_type(4))) float  floatx4;
typedef __attribute__((ext_vector_type(16))) float floatx16;
typedef __attribute__((ext_vector_type(2))) unsigned int uint2v;

__device__ __forceinline__ unsigned short f2bf(float f) {
  unsigned int x = __builtin_bit_cast(unsigned int, f);
  x += 0x7fffu + ((x >> 16) & 1u);   // RNE; inputs finite
  return (unsigned short)(x >> 16);
}
__device__ __forceinline__ unsigned int cvt_pk_bf16(float lo, float hi) {
  unsigned int r;
  asm("v_cvt_pk_bf16_f32 %0, %1, %2" : "=v"(r) : "v"(lo), "v"(hi));
  return r;
}
// async global->LDS, 16B per lane; lds dest = wave-uniform base + lane*16
__device__ __forceinline__ void gload_lds16(const unsigned short* g, unsigned short* l) {
  __builtin_amdgcn_global_load_lds(
      (const __attribute__((address_space(1))) unsigned int*)g,
      (__attribute__((address_space(3))) unsigned int*)l, 16, 0, 0);
}

// ---------------- cast x (fp32 -> bf16) ----------------
__global__ void cast_bf16(const float* __restrict__ in, unsigned short* __restrict__ out) {
  int i = (blockIdx.x * 256 + threadIdx.x) * 4;
  floatx4 v = *(const floatx4*)(in + i);
  unsigned short o[4];
  o[0] = f2bf(v[0]); o[1] = f2bf(v[1]); o[2] = f2bf(v[2]); o[3] = f2bf(v[3]);
  *(unsigned long long*)(out + i) = *(unsigned long long*)o;
}

// ------------- transpose + cast weights: T[n][k] = bf16(W[k][n]) -------------
__global__ void transW(const float* __restrict__ W0, const float* __restrict__ W1,
                       const float* __restrict__ W2, const float* __restrict__ W3,
                       unsigned short* __restrict__ T0, unsigned short* __restrict__ T1,
                       unsigned short* __restrict__ T2, unsigned short* __restrict__ T3) {
  const float* W; unsigned short* T;
  int z = blockIdx.z;
  if (z == 0)      { W = W0; T = T0; }
  else if (z == 1) { W = W1; T = T1; }
  else if (z == 2) { W = W2; T = T2; }
  else             { W = W3; T = T3; }
  __shared__ float tile[32][33];
  int bx = blockIdx.x * 32, by = blockIdx.y * 32;
  int tx = threadIdx.x, ty = threadIdx.y;
  #pragma unroll
  for (int j = 0; j < 4; j++)
    tile[ty + j*8][tx] = W[(size_t)(by + ty + j*8) * HID_ + bx + tx];
  __syncthreads();
  #pragma unroll
  for (int j = 0; j < 4; j++)
    T[(size_t)(bx + ty + j*8) * HID_ + by + tx] = f2bf(tile[tx][ty + j*8]);
}

// ---------------- GEMM: C[M,N] = A[M,K] @ Bt[N,K]^T (+bias) ----------------
// MODE 0: QKV producer. z=0: Q bf16, rope + scale c1. z=1: K bf16, rope.
//         z=2: V bf16 written TRANSPOSED into Vt[b][h][d][s].
template <int MODE>
__global__ __launch_bounds__(256) void gemm_bt(
    const unsigned short* __restrict__ A,
    const unsigned short* __restrict__ Bt0, const unsigned short* __restrict__ Bt1,
    const unsigned short* __restrict__ Bt2,
    const float* __restrict__ bias0, const float* __restrict__ bias1,
    const float* __restrict__ bias2,
    void* __restrict__ out0, void* __restrict__ out1, void* __restrict__ out2,
    const float* __restrict__ sins, float sc0)
{
  const unsigned short* Bt; const float* bias; void* Out; float sc;
  if (blockIdx.z == 0)      { Bt = Bt0; bias = bias0; Out = out0; sc = sc0; }
  else if (blockIdx.z == 1) { Bt = Bt1; bias = bias1; Out = out1; sc = 1.f; }
  else                      { Bt = Bt2; bias = bias2; Out = out2; sc = 1.f; }
  const int K = HID_, N = HID_;
  int m0 = blockIdx.y * 128, n0 = blockIdx.x * 128;
  __shared__ alignas(16) unsigned short sA[128 * 32];
  __shared__ alignas(16) unsigned short sB[128 * 32];
  int t = threadIdx.x;
  int lane = t & 63, wave = t >> 6;
  int quad = lane >> 4, l16 = lane & 15;
  int wr = wave >> 1, wc = wave & 1;

  int srow = (lane >> 2), scol = (lane & 3) * 8;
  const unsigned short* gA0 = A  + (size_t)(m0 + wave*32 +  0 + srow) * K + scol;
  const unsigned short* gA1 = A  + (size_t)(m0 + wave*32 + 16 + srow) * K + scol;
  const unsigned short* gB0 = Bt + (size_t)(n0 + wave*32 +  0 + srow) * K + scol;
  const unsigned short* gB1 = Bt + (size_t)(n0 + wave*32 + 16 + srow) * K + scol;
  unsigned short* lA0 = sA + (wave*32 +  0) * 32;
  unsigned short* lA1 = sA + (wave*32 + 16) * 32;
  unsigned short* lB0 = sB + (wave*32 +  0) * 32;
  unsigned short* lB1 = sB + (wave*32 + 16) * 32;

  floatx4 acc[4][4];
  #pragma unroll
  for (int i = 0; i < 4; i++)
    #pragma unroll
    for (int j = 0; j < 4; j++)
      acc[i][j] = (floatx4){0.f, 0.f, 0.f, 0.f};

  for (int k0 = 0; k0 < K; k0 += 32) {
    gload_lds16(gA0 + k0, lA0);
    gload_lds16(gA1 + k0, lA1);
    gload_lds16(gB0 + k0, lB0);
    gload_lds16(gB1 + k0, lB1);
    __syncthreads();
    short8 af[4], bf[4];
    #pragma unroll
    for (int i = 0; i < 4; i++) {
      af[i] = *(const short8*)(sA + (wr * 64 + i * 16 + l16) * 32 + quad * 8);
      bf[i] = *(const short8*)(sB + (wc * 64 + i * 16 + l16) * 32 + quad * 8);
    }
    #pragma unroll
    for (int i = 0; i < 4; i++)
      #pragma unroll
      for (int j = 0; j < 4; j++)
        acc[i][j] = __builtin_amdgcn_mfma_f32_16x16x32_bf16(af[i], bf[j], acc[i][j], 0, 0, 0);
    __syncthreads();
  }

  // Epilogue. C/D layout: col = lane&15, row = quad*4 + reg.
  #pragma unroll
  for (int i = 0; i < 4; i++) {
    int mbase = m0 + wr * 64 + i * 16 + quad * 4;
    #pragma unroll
    for (int j = 0; j < 4; j++) {
      int n = n0 + wc * 64 + j * 16 + l16;
      float bv = bias ? bias[n] : 0.f;
      if (MODE == 1) {
        #pragma unroll
        for (int r = 0; r < 4; r++)
          ((float*)Out)[(size_t)(mbase + r) * N + n] = acc[i][j][r] + bv;
      } else if (blockIdx.z == 2) {
        // V: write transposed Vt[((b*16+h)*64+dd)*2048 + s], 4 consecutive s packed
        int bb = mbase >> 11, ss = mbase & 2047;
        int hh = n >> 6, dd = n & 63;
        unsigned short pk[4];
        #pragma unroll
        for (int r = 0; r < 4; r++) pk[r] = f2bf(acc[i][j][r] + bv);
        *(unsigned long long*)((unsigned short*)Out +
            (((size_t)(bb * H_ + hh) * D_ + dd) * S_ + ss)) = *(unsigned long long*)pk;
      } else if (j < 2) {
        // rope columns: head-dim index jh = j*16 + l16 < 32 (wave-uniform branch)
        int jh = j * 16 + l16;
        #pragma unroll
        for (int r = 0; r < 4; r++) {
          int row = mbase + r, bb = row >> 11, ss = row & 2047;
          float sn = sins[((size_t)(bb * 2 + 0) * S_ + ss) * ROT_ + jh];
          float cs = sins[((size_t)(bb * 2 + 1) * S_ + ss) * ROT_ + jh];
          float f = (jh & 1) ? (cs + sn) : (cs - sn);
          ((unsigned short*)Out)[(size_t)row * N + n] = f2bf((acc[i][j][r] + bv) * f * sc);
        }
      } else {
        #pragma unroll
        for (int r = 0; r < 4; r++)
          ((unsigned short*)Out)[(size_t)(mbase + r) * N + n] = f2bf((acc[i][j][r] + bv) * sc);
      }
    }
  }
}

// ---- final projection GEMM: 128(M)x64(N) tile, fp32 out, 512 blocks (2/CU) ----
__global__ __launch_bounds__(256) void gemm_bt64(
    const unsigned short* __restrict__ A, const unsigned short* __restrict__ Bt,
    float* __restrict__ Out)
{
  const int K = HID_, N = HID_;
  int m0 = blockIdx.y * 128, n0 = blockIdx.x * 64;
  __shared__ alignas(16) unsigned short sA[128 * 32];
  __shared__ alignas(16) unsigned short sB[64 * 32];
  int t = threadIdx.x;
  int lane = t & 63, wave = t >> 6;
  int quad = lane >> 4, l16 = lane & 15;
  int wr = wave >> 1, wc = wave & 1;   // per-wave 64(M) x 32(N)

  int srow = lane >> 2, scol = (lane & 3) * 8;
  const unsigned short* gA0 = A  + (size_t)(m0 + wave*32 +  0 + srow) * K + scol;
  const unsigned short* gA1 = A  + (size_t)(m0 + wave*32 + 16 + srow) * K + scol;
  const unsigned short* gB0 = Bt + (size_t)(n0 + wave*16 + srow) * K + scol;
  unsigned short* lA0 = sA + (wave*32 +  0) * 32;
  unsigned short* lA1 = sA + (wave*32 + 16) * 32;
  unsigned short* lB0 = sB + (wave*16) * 32;

  floatx4 acc[4][2];
  #pragma unroll
  for (int i = 0; i < 4; i++)
    #pragma unroll
    for (int j = 0; j < 2; j++)
      acc[i][j] = (floatx4){0.f, 0.f, 0.f, 0.f};

  for (int k0 = 0; k0 < K; k0 += 32) {
    gload_lds16(gA0 + k0, lA0);
    gload_lds16(gA1 + k0, lA1);
    gload_lds16(gB0 + k0, lB0);
    __syncthreads();
    short8 af[4], bf[2];
    #pragma unroll
    for (int i = 0; i < 4; i++)
      af[i] = *(const short8*)(sA + (wr * 64 + i * 16 + l16) * 32 + quad * 8);
    #pragma unroll
    for (int j = 0; j < 2; j++)
      bf[j] = *(const short8*)(sB + (wc * 32 + j * 16 + l16) * 32 + quad * 8);
    #pragma unroll
    for (int i = 0; i < 4; i++)
      #pragma unroll
      for (int j = 0; j < 2; j++)
        acc[i][j] = __builtin_amdgcn_mfma_f32_16x16x32_bf16(af[i], bf[j], acc[i][j], 0, 0, 0);
    __syncthreads();
  }

  #pragma unroll
  for (int i = 0; i < 4; i++) {
    int mbase = m0 + wr * 64 + i * 16 + quad * 4;
    #pragma unroll
    for (int j = 0; j < 2; j++) {
      int n = n0 + wc * 32 + j * 16 + l16;
      #pragma unroll
      for (int r = 0; r < 4; r++)
        Out[(size_t)(mbase + r) * N + n] = acc[i][j][r];
    }
  }
}

// ---------------- flash attention: S^T trick + in-block split-K ----------------
// 8 waves: group g = wave>>2 handles k-half [g*1024, (g+1)*1024) for the SAME
// 128 q-rows (wave wg = wave&3 owns 32 q). Fixed-max exp2 softmax -> partial
// (O,l) of the two halves combine by pure addition via a 32KB LDS exchange.
// 512 blocks x 8 waves, 2 blocks/CU (LDS 73728B limits to 2 anyway).
// __launch_bounds__ second arg observed as min-BLOCKS/CU on hipcc: (512,4)
// capped VGPR at 64 -> 115MB scratch spill traffic (R1). (512,2) -> cap 128,
// the ~104-reg body fits spill-free, and 2 blocks/CU = 16 waves/CU holds.
__global__ __launch_bounds__(512, 2) void attn(
    const unsigned short* __restrict__ Q, const unsigned short* __restrict__ Kb,
    const unsigned short* __restrict__ Vt, const float* __restrict__ bias,
    unsigned short* __restrict__ Out)
{
  int b = blockIdx.z, h = blockIdx.y;
  int t = threadIdx.x;
  int lane = t & 63, wave = t >> 6;
  int g = wave >> 2, wg = wave & 3;
  int l32 = lane & 31, hl = lane >> 5;
  int q0 = blockIdx.x * 128 + wg * 32;
  const int RS = H_ * D_;
  const int NT = S_ / 128;   // 16 tiles of 64 keys per k-half

  // per group g: [Kbuf0][Kbuf1][Vbuf0][Vbuf1], each 64*72 shorts (pad 72)
  __shared__ alignas(16) unsigned short smem[2 * 18432];
  unsigned short* sKg = smem + g * 18432;
  unsigned short* sVg = sKg + 9216;

  const unsigned short* Qbase = Q + ((size_t)(b * S_) * H_ + h) * D_;
  const unsigned short* Kbase = Kb + ((size_t)(b * S_) * H_ + h) * D_;
  const unsigned short* Vbase = Vt + ((size_t)(b * H_) + h) * D_ * S_;

  // Q B-frags (n=q=lane&31, k=d=16s+8hl+j), fixed for whole kernel
  short8 qf[4];
  {
    const unsigned short* qp = Qbase + (size_t)(q0 + l32) * RS + 8 * hl;
    qf[0] = *(const short8*)(qp);
    qf[1] = *(const short8*)(qp + 16);
    qf[2] = *(const short8*)(qp + 32);
    qf[3] = *(const short8*)(qp + 48);
  }

  // staging: group-local thread tg -> row tg>>2, quarter tg&3, 2x16B chunks
  int tg = t & 255;
  int srow = tg >> 2, sq = tg & 3;
  const unsigned short* gK = Kbase + (size_t)(g * 1024 + srow) * RS + sq * 16;
  const unsigned short* gV = Vbase + (size_t)srow * S_ + g * 1024 + sq * 16;
  const int wOff = srow * 72 + sq * 16;

  const float* bp = bias + (size_t)b * S_ * S_ + (size_t)(q0 + l32) * S_ + g * 1024 + 4 * hl;

  float l_run = 0.f;
  floatx16 o0, o1;
  #pragma unroll
  for (int r = 0; r < 16; r++) { o0[r] = 0.f; o1[r] = 0.f; }

  // tile 0 of this half -> LDS buf 0; prefetch tile 1 into regs
  floatx4 kp[2], vp[2];
  kp[0] = *(const floatx4*)(gK);     kp[1] = *(const floatx4*)(gK + 8);
  vp[0] = *(const floatx4*)(gV);     vp[1] = *(const floatx4*)(gV + 8);
  *(floatx4*)(sKg + wOff)     = kp[0];
  *(floatx4*)(sKg + wOff + 8) = kp[1];
  *(floatx4*)(sVg + wOff)     = vp[0];
  *(floatx4*)(sVg + wOff + 8) = vp[1];
  kp[0] = *(const floatx4*)(gK + (size_t)64 * RS);
  kp[1] = *(const floatx4*)(gK + (size_t)64 * RS + 8);
  vp[0] = *(const floatx4*)(gV + 64);
  vp[1] = *(const floatx4*)(gV + 64 + 8);

  for (int it = 0; it < NT; ++it) {
    int cur = it & 1, nxt = cur ^ 1;
    __syncthreads();

    if (it < NT - 1) {
      *(floatx4*)(sKg + nxt * 4608 + wOff)     = kp[0];
      *(floatx4*)(sKg + nxt * 4608 + wOff + 8) = kp[1];
      *(floatx4*)(sVg + nxt * 4608 + wOff)     = vp[0];
      *(floatx4*)(sVg + nxt * 4608 + wOff + 8) = vp[1];
    }
    {
      int k2 = ((it + 2) & (NT - 1)) * 64;
      kp[0] = *(const floatx4*)(gK + (size_t)k2 * RS);
      kp[1] = *(const floatx4*)(gK + (size_t)k2 * RS + 8);
      vp[0] = *(const floatx4*)(gV + k2);
      vp[1] = *(const floatx4*)(gV + k2 + 8);
    }

    // bias loads early (independent of LDS)
    floatx4 bl[8];
    #pragma unroll
    for (int cc = 0; cc < 2; cc++)
      #pragma unroll
      for (int rg = 0; rg < 4; rg++)
        bl[cc * 4 + rg] = *(const floatx4*)(bp + it * 64 + cc * 32 + 8 * rg);

    const unsigned short* sKc = sKg + cur * 4608;
    const unsigned short* sVc = sVg + cur * 4608;

    // S^T: D[m=k][n=q], M-blocks cc over 64 k, K-steps over d=64
    floatx16 st[2];
    __builtin_amdgcn_s_setprio(1);
    #pragma unroll
    for (int cc = 0; cc < 2; cc++) {
      floatx16 s;
      #pragma unroll
      for (int r = 0; r < 16; r++) s[r] = 0.f;
      #pragma unroll
      for (int ks = 0; ks < 4; ks++) {
        short8 kf = *(const short8*)(sKc + (cc * 32 + l32) * 72 + 16 * ks + 8 * hl);
        s = __builtin_amdgcn_mfma_f32_32x32x16_bf16(kf, qf[ks], s, 0, 0, 0);
      }
      st[cc] = s;
    }
    __builtin_amdgcn_s_setprio(0);

    // p = exp2(s); l += p; pack p*bias into 32x32x8 A-frags (k=4hl+j == C-layout)
    short4v pf[2][4];
    #pragma unroll
    for (int cc = 0; cc < 2; cc++)
      #pragma unroll
      for (int rg = 0; rg < 4; rg++) {
        float p0 = __builtin_amdgcn_exp2f(st[cc][rg * 4 + 0]);
        float p1 = __builtin_amdgcn_exp2f(st[cc][rg * 4 + 1]);
        float p2 = __builtin_amdgcn_exp2f(st[cc][rg * 4 + 2]);
        float p3 = __builtin_amdgcn_exp2f(st[cc][rg * 4 + 3]);
        l_run += (p0 + p1) + (p2 + p3);
        uint2v u;
        u[0] = cvt_pk_bf16(p0 * bl[cc * 4 + rg][0], p1 * bl[cc * 4 + rg][1]);
        u[1] = cvt_pk_bf16(p2 * bl[cc * 4 + rg][2], p3 * bl[cc * 4 + rg][3]);
        pf[cc][rg] = __builtin_bit_cast(short4v, u);
      }

    // O += P @ V : 32x32x8, A=pf (regs), B=V[k][d] from sV[d][k]
    __builtin_amdgcn_s_setprio(1);
    #pragma unroll
    for (int cc = 0; cc < 2; cc++)
      #pragma unroll
      for (int gg = 0; gg < 4; gg++) {
        int kcol = cc * 32 + 8 * gg + 4 * hl;
        short4v vf0 = *(const short4v*)(sVc + (l32)      * 72 + kcol);
        short4v vf1 = *(const short4v*)(sVc + (32 + l32) * 72 + kcol);
        o0 = __builtin_amdgcn_mfma_f32_32x32x8bf16_1k(pf[cc][gg], vf0, o0, 0, 0, 0);
        o1 = __builtin_amdgcn_mfma_f32_32x32x8bf16_1k(pf[cc][gg], vf1, o1, 0, 0, 0);
      }
    __builtin_amdgcn_s_setprio(0);
  }

  // full k-half denominator for q-row l32 (partner half-lane has the other half)
  float l2 = l_run + __shfl_xor(l_run, 32);

  // combine the two k-halves through group-1's LDS region (done with its K/V)
  float* sO = (float*)(smem + 18432);   // 128 q x 64 d fp32 = 32KB
  float* sL = sO + 128 * 64;            // 128 floats

  __syncthreads();
  if (g == 1) {
    #pragma unroll
    for (int r = 0; r < 16; r++) {
      int ql = (r & 3) + 8 * (r >> 2) + 4 * hl;
      sO[(wg * 32 + ql) * 64 + l32]      = o0[r];
      sO[(wg * 32 + ql) * 64 + 32 + l32] = o1[r];
    }
    if (hl == 0) sL[wg * 32 + l32] = l2;
  }
  __syncthreads();
  if (g == 0) {
    float linv = __builtin_amdgcn_rcpf(l2 + sL[wg * 32 + l32]);
    #pragma unroll
    for (int r = 0; r < 16; r++) {
      int ql = (r & 3) + 8 * (r >> 2) + 4 * hl;
      float sc = __shfl(linv, ql);
      size_t base = ((size_t)(b * S_ + q0 + ql) * H_ + h) * D_;
      float a0 = o0[r] + sO[(wg * 32 + ql) * 64 + l32];
      float a1 = o1[r] + sO[(wg * 32 + ql) * 64 + 32 + l32];
      Out[base + l32]      = f2bf(a0 * sc);
      Out[base + 32 + l32] = f2bf(a1 * sc);
    }
  }
}

// ---------------- launch ----------------
extern "C" void kernel_launch(void* const* d_in, const int* in_sizes, int n_in,
                              void* d_out, int out_size, void* d_ws, size_t ws_size,
                              hipStream_t stream) {
  (void)in_sizes; (void)n_in; (void)out_size; (void)ws_size;
  const float* x    = (const float*)d_in[0];
  const float* sins = (const float*)d_in[1];
  const float* ab   = (const float*)d_in[2];
  const float* Wq   = (const float*)d_in[3];
  const float* bq   = (const float*)d_in[4];
  const float* Wk   = (const float*)d_in[5];
  const float* bk   = (const float*)d_in[6];
  const float* Wv   = (const float*)d_in[7];
  const float* bv   = (const float*)d_in[8];
  const float* Wo   = (const float*)d_in[9];
  float* out = (float*)d_out;
  char* ws = (char*)d_ws;

  unsigned short* xb  = (unsigned short*)(ws);                       // 8 MB
  unsigned short* Wqt = (unsigned short*)(ws + ((size_t) 8 << 20));  // 2 MB each
  unsigned short* Wkt = (unsigned short*)(ws + ((size_t)10 << 20));
  unsigned short* Wvt = (unsigned short*)(ws + ((size_t)12 << 20));
  unsigned short* Wot = (unsigned short*)(ws + ((size_t)14 << 20));
  unsigned short* Qb  = (unsigned short*)(ws + ((size_t)16 << 20));  // 8 MB
  unsigned short* Kb  = (unsigned short*)(ws + ((size_t)24 << 20));  // 8 MB
  unsigned short* Vtb = (unsigned short*)(ws + ((size_t)32 << 20));  // 8 MB, [b][h][d][s]
  unsigned short* Ab  = (unsigned short*)(ws + ((size_t)40 << 20));  // 8 MB

  const float c1 = 0.125f * 1.44269504088896f;  // 1/sqrt(D) * log2(e), folded into Q

  cast_bf16<<<dim3((M_ * HID_) / (256 * 4)), dim3(256), 0, stream>>>(x, xb);
  transW<<<dim3(32, 32, 4), dim3(32, 8), 0, stream>>>(Wq, Wk, Wv, Wo, Wqt, Wkt, Wvt, Wot);
  gemm_bt<0><<<dim3(8, 32, 3), dim3(256), 0, stream>>>(xb, Wqt, Wkt, Wvt, bq, bk, bv,
                                                       Qb, Kb, Vtb, sins, c1);
  attn<<<dim3(S_ / 128, H_, B_), dim3(512), 0, stream>>>(Qb, Kb, Vtb, ab, Ab);
  gemm_bt64<<<dim3(HID_ / 64, M_ / 128), dim3(256), 0, stream>>>(Ab, Wot, out);
}

// Round 3
// 272.058 us; speedup vs baseline: 1.1639x; 1.0472x over previous
//
#include <hip/hip_runtime.h>
#include <math.h>

#define B_   2
#define S_   2048
#define HID_ 1024
#define D_   64
#define H_   16
#define ROT_ 32
#define M_   (B_*S_)

typedef __attribute__((ext_vector_type(4))) short  short4v;
typedef __attribute__((ext_vector_type(8))) short  short8;
typedef __attribute__((ext_vector_type(4))) float  floatx4;
typedef __attribute__((ext_vector_type(16))) float floatx16;
typedef __attribute__((ext_vector_type(2))) unsigned int uint2v;

__device__ __forceinline__ unsigned short f2bf(float f) {
  unsigned int x = __builtin_bit_cast(unsigned int, f);
  x += 0x7fffu + ((x >> 16) & 1u);   // RNE; inputs finite
  return (unsigned short)(x >> 16);
}
__device__ __forceinline__ unsigned int cvt_pk_bf16(float lo, float hi) {
  unsigned int r;
  asm("v_cvt_pk_bf16_f32 %0, %1, %2" : "=v"(r) : "v"(lo), "v"(hi));
  return r;
}
// async global->LDS, 16B per lane; lds dest = wave-uniform base + lane*16
__device__ __forceinline__ void gload_lds16(const unsigned short* g, unsigned short* l) {
  __builtin_amdgcn_global_load_lds(
      (const __attribute__((address_space(1))) unsigned int*)g,
      (__attribute__((address_space(3))) unsigned int*)l, 16, 0, 0);
}

// ---------------- cast x (fp32 -> bf16) ----------------
__global__ void cast_bf16(const float* __restrict__ in, unsigned short* __restrict__ out) {
  int i = (blockIdx.x * 256 + threadIdx.x) * 4;
  floatx4 v = *(const floatx4*)(in + i);
  unsigned short o[4];
  o[0] = f2bf(v[0]); o[1] = f2bf(v[1]); o[2] = f2bf(v[2]); o[3] = f2bf(v[3]);
  *(unsigned long long*)(out + i) = *(unsigned long long*)o;
}

// ------------- transpose + cast weights: T[n][k] = bf16(W[k][n]) -------------
__global__ void transW(const float* __restrict__ W0, const float* __restrict__ W1,
                       const float* __restrict__ W2, const float* __restrict__ W3,
                       unsigned short* __restrict__ T0, unsigned short* __restrict__ T1,
                       unsigned short* __restrict__ T2, unsigned short* __restrict__ T3) {
  const float* W; unsigned short* T;
  int z = blockIdx.z;
  if (z == 0)      { W = W0; T = T0; }
  else if (z == 1) { W = W1; T = T1; }
  else if (z == 2) { W = W2; T = T2; }
  else             { W = W3; T = T3; }
  __shared__ float tile[32][33];
  int bx = blockIdx.x * 32, by = blockIdx.y * 32;
  int tx = threadIdx.x, ty = threadIdx.y;
  #pragma unroll
  for (int j = 0; j < 4; j++)
    tile[ty + j*8][tx] = W[(size_t)(by + ty + j*8) * HID_ + bx + tx];
  __syncthreads();
  #pragma unroll
  for (int j = 0; j < 4; j++)
    T[(size_t)(bx + ty + j*8) * HID_ + by + tx] = f2bf(tile[tx][ty + j*8]);
}

// ---------------- GEMM: C[M,N] = A[M,K] @ Bt[N,K]^T (+bias) ----------------
// MODE 0: QKV producer. z=0: Q bf16, rope + scale c1. z=1: K bf16, rope.
//         z=2: V bf16 written TRANSPOSED into Vt[b][h][d][s].
template <int MODE>
__global__ __launch_bounds__(256) void gemm_bt(
    const unsigned short* __restrict__ A,
    const unsigned short* __restrict__ Bt0, const unsigned short* __restrict__ Bt1,
    const unsigned short* __restrict__ Bt2,
    const float* __restrict__ bias0, const float* __restrict__ bias1,
    const float* __restrict__ bias2,
    void* __restrict__ out0, void* __restrict__ out1, void* __restrict__ out2,
    const float* __restrict__ sins, float sc0)
{
  const unsigned short* Bt; const float* bias; void* Out; float sc;
  if (blockIdx.z == 0)      { Bt = Bt0; bias = bias0; Out = out0; sc = sc0; }
  else if (blockIdx.z == 1) { Bt = Bt1; bias = bias1; Out = out1; sc = 1.f; }
  else                      { Bt = Bt2; bias = bias2; Out = out2; sc = 1.f; }
  const int K = HID_, N = HID_;
  int m0 = blockIdx.y * 128, n0 = blockIdx.x * 128;
  __shared__ alignas(16) unsigned short sA[128 * 32];
  __shared__ alignas(16) unsigned short sB[128 * 32];
  int t = threadIdx.x;
  int lane = t & 63, wave = t >> 6;
  int quad = lane >> 4, l16 = lane & 15;
  int wr = wave >> 1, wc = wave & 1;

  int srow = (lane >> 2), scol = (lane & 3) * 8;
  const unsigned short* gA0 = A  + (size_t)(m0 + wave*32 +  0 + srow) * K + scol;
  const unsigned short* gA1 = A  + (size_t)(m0 + wave*32 + 16 + srow) * K + scol;
  const unsigned short* gB0 = Bt + (size_t)(n0 + wave*32 +  0 + srow) * K + scol;
  const unsigned short* gB1 = Bt + (size_t)(n0 + wave*32 + 16 + srow) * K + scol;
  unsigned short* lA0 = sA + (wave*32 +  0) * 32;
  unsigned short* lA1 = sA + (wave*32 + 16) * 32;
  unsigned short* lB0 = sB + (wave*32 +  0) * 32;
  unsigned short* lB1 = sB + (wave*32 + 16) * 32;

  floatx4 acc[4][4];
  #pragma unroll
  for (int i = 0; i < 4; i++)
    #pragma unroll
    for (int j = 0; j < 4; j++)
      acc[i][j] = (floatx4){0.f, 0.f, 0.f, 0.f};

  for (int k0 = 0; k0 < K; k0 += 32) {
    gload_lds16(gA0 + k0, lA0);
    gload_lds16(gA1 + k0, lA1);
    gload_lds16(gB0 + k0, lB0);
    gload_lds16(gB1 + k0, lB1);
    __syncthreads();
    short8 af[4], bf[4];
    #pragma unroll
    for (int i = 0; i < 4; i++) {
      af[i] = *(const short8*)(sA + (wr * 64 + i * 16 + l16) * 32 + quad * 8);
      bf[i] = *(const short8*)(sB + (wc * 64 + i * 16 + l16) * 32 + quad * 8);
    }
    #pragma unroll
    for (int i = 0; i < 4; i++)
      #pragma unroll
      for (int j = 0; j < 4; j++)
        acc[i][j] = __builtin_amdgcn_mfma_f32_16x16x32_bf16(af[i], bf[j], acc[i][j], 0, 0, 0);
    __syncthreads();
  }

  // Epilogue. C/D layout: col = lane&15, row = quad*4 + reg.
  #pragma unroll
  for (int i = 0; i < 4; i++) {
    int mbase = m0 + wr * 64 + i * 16 + quad * 4;
    #pragma unroll
    for (int j = 0; j < 4; j++) {
      int n = n0 + wc * 64 + j * 16 + l16;
      float bv = bias ? bias[n] : 0.f;
      if (MODE == 1) {
        #pragma unroll
        for (int r = 0; r < 4; r++)
          ((float*)Out)[(size_t)(mbase + r) * N + n] = acc[i][j][r] + bv;
      } else if (blockIdx.z == 2) {
        // V: write transposed Vt[((b*16+h)*64+dd)*2048 + s], 4 consecutive s packed
        int bb = mbase >> 11, ss = mbase & 2047;
        int hh = n >> 6, dd = n & 63;
        unsigned short pk[4];
        #pragma unroll
        for (int r = 0; r < 4; r++) pk[r] = f2bf(acc[i][j][r] + bv);
        *(unsigned long long*)((unsigned short*)Out +
            (((size_t)(bb * H_ + hh) * D_ + dd) * S_ + ss)) = *(unsigned long long*)pk;
      } else if (j < 2) {
        // rope columns: head-dim index jh = j*16 + l16 < 32 (wave-uniform branch)
        int jh = j * 16 + l16;
        #pragma unroll
        for (int r = 0; r < 4; r++) {
          int row = mbase + r, bb = row >> 11, ss = row & 2047;
          float sn = sins[((size_t)(bb * 2 + 0) * S_ + ss) * ROT_ + jh];
          float cs = sins[((size_t)(bb * 2 + 1) * S_ + ss) * ROT_ + jh];
          float f = (jh & 1) ? (cs + sn) : (cs - sn);
          ((unsigned short*)Out)[(size_t)row * N + n] = f2bf((acc[i][j][r] + bv) * f * sc);
        }
      } else {
        #pragma unroll
        for (int r = 0; r < 4; r++)
          ((unsigned short*)Out)[(size_t)(mbase + r) * N + n] = f2bf((acc[i][j][r] + bv) * sc);
      }
    }
  }
}

// ---- final projection GEMM: 128(M)x64(N) tile, fp32 out, 512 blocks (2/CU) ----
__global__ __launch_bounds__(256) void gemm_bt64(
    const unsigned short* __restrict__ A, const unsigned short* __restrict__ Bt,
    float* __restrict__ Out)
{
  const int K = HID_, N = HID_;
  int m0 = blockIdx.y * 128, n0 = blockIdx.x * 64;
  __shared__ alignas(16) unsigned short sA[128 * 32];
  __shared__ alignas(16) unsigned short sB[64 * 32];
  int t = threadIdx.x;
  int lane = t & 63, wave = t >> 6;
  int quad = lane >> 4, l16 = lane & 15;
  int wr = wave >> 1, wc = wave & 1;   // per-wave 64(M) x 32(N)

  int srow = lane >> 2, scol = (lane & 3) * 8;
  const unsigned short* gA0 = A  + (size_t)(m0 + wave*32 +  0 + srow) * K + scol;
  const unsigned short* gA1 = A  + (size_t)(m0 + wave*32 + 16 + srow) * K + scol;
  const unsigned short* gB0 = Bt + (size_t)(n0 + wave*16 + srow) * K + scol;
  unsigned short* lA0 = sA + (wave*32 +  0) * 32;
  unsigned short* lA1 = sA + (wave*32 + 16) * 32;
  unsigned short* lB0 = sB + (wave*16) * 32;

  floatx4 acc[4][2];
  #pragma unroll
  for (int i = 0; i < 4; i++)
    #pragma unroll
    for (int j = 0; j < 2; j++)
      acc[i][j] = (floatx4){0.f, 0.f, 0.f, 0.f};

  for (int k0 = 0; k0 < K; k0 += 32) {
    gload_lds16(gA0 + k0, lA0);
    gload_lds16(gA1 + k0, lA1);
    gload_lds16(gB0 + k0, lB0);
    __syncthreads();
    short8 af[4], bf[2];
    #pragma unroll
    for (int i = 0; i < 4; i++)
      af[i] = *(const short8*)(sA + (wr * 64 + i * 16 + l16) * 32 + quad * 8);
    #pragma unroll
    for (int j = 0; j < 2; j++)
      bf[j] = *(const short8*)(sB + (wc * 32 + j * 16 + l16) * 32 + quad * 8);
    #pragma unroll
    for (int i = 0; i < 4; i++)
      #pragma unroll
      for (int j = 0; j < 2; j++)
        acc[i][j] = __builtin_amdgcn_mfma_f32_16x16x32_bf16(af[i], bf[j], acc[i][j], 0, 0, 0);
    __syncthreads();
  }

  #pragma unroll
  for (int i = 0; i < 4; i++) {
    int mbase = m0 + wr * 64 + i * 16 + quad * 4;
    #pragma unroll
    for (int j = 0; j < 2; j++) {
      int n = n0 + wc * 32 + j * 16 + l16;
      #pragma unroll
      for (int r = 0; r < 4; r++)
        Out[(size_t)(mbase + r) * N + n] = acc[i][j][r];
    }
  }
}

// ---------------- flash attention: S^T trick + in-block split-K ----------------
// 8 waves: group g = wave>>2 handles k-half [g*1024, (g+1)*1024) for the SAME
// 128 q-rows (wave wg = wave&3 owns 32 q). Fixed-max exp2 softmax -> partial
// (O,l) of the two halves combine by pure addition via a 32KB LDS exchange.
// 512 blocks x 8 waves, 2 blocks/CU. R2 lesson: occupancy alone didn't help --
// all waves stall together on the once-read 32MB fp32 bias stream (issued and
// consumed within ~150 cyc, HBM latency ~900, barrier-lockstep couples waves).
// R3: double-buffer the bias in registers (T14) -> vmcnt wait lands a full
// tile (~1500 cyc) after issue. +32 VGPR, still under the 128 cap.
__global__ __launch_bounds__(512, 2) void attn(
    const unsigned short* __restrict__ Q, const unsigned short* __restrict__ Kb,
    const unsigned short* __restrict__ Vt, const float* __restrict__ bias,
    unsigned short* __restrict__ Out)
{
  int b = blockIdx.z, h = blockIdx.y;
  int t = threadIdx.x;
  int lane = t & 63, wave = t >> 6;
  int g = wave >> 2, wg = wave & 3;
  int l32 = lane & 31, hl = lane >> 5;
  int q0 = blockIdx.x * 128 + wg * 32;
  const int RS = H_ * D_;
  const int NT = S_ / 128;   // 16 tiles of 64 keys per k-half

  // per group g: [Kbuf0][Kbuf1][Vbuf0][Vbuf1], each 64*72 shorts (pad 72)
  __shared__ alignas(16) unsigned short smem[2 * 18432];
  unsigned short* sKg = smem + g * 18432;
  unsigned short* sVg = sKg + 9216;

  const unsigned short* Qbase = Q + ((size_t)(b * S_) * H_ + h) * D_;
  const unsigned short* Kbase = Kb + ((size_t)(b * S_) * H_ + h) * D_;
  const unsigned short* Vbase = Vt + ((size_t)(b * H_) + h) * D_ * S_;

  // Q B-frags (n=q=lane&31, k=d=16s+8hl+j), fixed for whole kernel
  short8 qf[4];
  {
    const unsigned short* qp = Qbase + (size_t)(q0 + l32) * RS + 8 * hl;
    qf[0] = *(const short8*)(qp);
    qf[1] = *(const short8*)(qp + 16);
    qf[2] = *(const short8*)(qp + 32);
    qf[3] = *(const short8*)(qp + 48);
  }

  // staging: group-local thread tg -> row tg>>2, quarter tg&3, 2x16B chunks
  int tg = t & 255;
  int srow = tg >> 2, sq = tg & 3;
  const unsigned short* gK = Kbase + (size_t)(g * 1024 + srow) * RS + sq * 16;
  const unsigned short* gV = Vbase + (size_t)srow * S_ + g * 1024 + sq * 16;
  const int wOff = srow * 72 + sq * 16;

  const float* bp = bias + (size_t)b * S_ * S_ + (size_t)(q0 + l32) * S_ + g * 1024 + 4 * hl;

  float l_run = 0.f;
  floatx16 o0, o1;
  #pragma unroll
  for (int r = 0; r < 16; r++) { o0[r] = 0.f; o1[r] = 0.f; }

  // tile 0 of this half -> LDS buf 0; prefetch tile 1 into regs
  floatx4 kp[2], vp[2];
  kp[0] = *(const floatx4*)(gK);     kp[1] = *(const floatx4*)(gK + 8);
  vp[0] = *(const floatx4*)(gV);     vp[1] = *(const floatx4*)(gV + 8);
  *(floatx4*)(sKg + wOff)     = kp[0];
  *(floatx4*)(sKg + wOff + 8) = kp[1];
  *(floatx4*)(sVg + wOff)     = vp[0];
  *(floatx4*)(sVg + wOff + 8) = vp[1];
  kp[0] = *(const floatx4*)(gK + (size_t)64 * RS);
  kp[1] = *(const floatx4*)(gK + (size_t)64 * RS + 8);
  vp[0] = *(const floatx4*)(gV + 64);
  vp[1] = *(const floatx4*)(gV + 64 + 8);

  // bias double-buffer: tile 0's bias loaded up front
  floatx4 bl_cur[8], bl_nxt[8];
  #pragma unroll
  for (int u = 0; u < 8; u++)
    bl_cur[u] = *(const floatx4*)(bp + (u >> 2) * 32 + (u & 3) * 8);

  #pragma unroll 2
  for (int it = 0; it < NT; ++it) {
    int cur = it & 1, nxt = cur ^ 1;
    __syncthreads();

    if (it < NT - 1) {
      *(floatx4*)(sKg + nxt * 4608 + wOff)     = kp[0];
      *(floatx4*)(sKg + nxt * 4608 + wOff + 8) = kp[1];
      *(floatx4*)(sVg + nxt * 4608 + wOff)     = vp[0];
      *(floatx4*)(sVg + nxt * 4608 + wOff + 8) = vp[1];
    }
    {
      int k2 = ((it + 2) & (NT - 1)) * 64;
      kp[0] = *(const floatx4*)(gK + (size_t)k2 * RS);
      kp[1] = *(const floatx4*)(gK + (size_t)k2 * RS + 8);
      vp[0] = *(const floatx4*)(gV + k2);
      vp[1] = *(const floatx4*)(gV + k2 + 8);
    }

    // issue NEXT tile's bias loads now; consumed next iteration (wrap: in-bounds)
    {
      int bnx = ((it + 1) & (NT - 1)) * 64;
      #pragma unroll
      for (int u = 0; u < 8; u++)
        bl_nxt[u] = *(const floatx4*)(bp + bnx + (u >> 2) * 32 + (u & 3) * 8);
    }

    const unsigned short* sKc = sKg + cur * 4608;
    const unsigned short* sVc = sVg + cur * 4608;

    // S^T: D[m=k][n=q], M-blocks cc over 64 k, K-steps over d=64
    floatx16 st[2];
    __builtin_amdgcn_s_setprio(1);
    #pragma unroll
    for (int cc = 0; cc < 2; cc++) {
      floatx16 s;
      #pragma unroll
      for (int r = 0; r < 16; r++) s[r] = 0.f;
      #pragma unroll
      for (int ks = 0; ks < 4; ks++) {
        short8 kf = *(const short8*)(sKc + (cc * 32 + l32) * 72 + 16 * ks + 8 * hl);
        s = __builtin_amdgcn_mfma_f32_32x32x16_bf16(kf, qf[ks], s, 0, 0, 0);
      }
      st[cc] = s;
    }
    __builtin_amdgcn_s_setprio(0);

    // p = exp2(s); l += p; pack p*bias into 32x32x8 A-frags (k=4hl+j == C-layout)
    short4v pf[2][4];
    #pragma unroll
    for (int cc = 0; cc < 2; cc++)
      #pragma unroll
      for (int rg = 0; rg < 4; rg++) {
        float p0 = __builtin_amdgcn_exp2f(st[cc][rg * 4 + 0]);
        float p1 = __builtin_amdgcn_exp2f(st[cc][rg * 4 + 1]);
        float p2 = __builtin_amdgcn_exp2f(st[cc][rg * 4 + 2]);
        float p3 = __builtin_amdgcn_exp2f(st[cc][rg * 4 + 3]);
        l_run += (p0 + p1) + (p2 + p3);
        uint2v u;
        u[0] = cvt_pk_bf16(p0 * bl_cur[cc * 4 + rg][0], p1 * bl_cur[cc * 4 + rg][1]);
        u[1] = cvt_pk_bf16(p2 * bl_cur[cc * 4 + rg][2], p3 * bl_cur[cc * 4 + rg][3]);
        pf[cc][rg] = __builtin_bit_cast(short4v, u);
      }

    // O += P @ V : 32x32x8, A=pf (regs), B=V[k][d] from sV[d][k]
    __builtin_amdgcn_s_setprio(1);
    #pragma unroll
    for (int cc = 0; cc < 2; cc++)
      #pragma unroll
      for (int gg = 0; gg < 4; gg++) {
        int kcol = cc * 32 + 8 * gg + 4 * hl;
        short4v vf0 = *(const short4v*)(sVc + (l32)      * 72 + kcol);
        short4v vf1 = *(const short4v*)(sVc + (32 + l32) * 72 + kcol);
        o0 = __builtin_amdgcn_mfma_f32_32x32x8bf16_1k(pf[cc][gg], vf0, o0, 0, 0, 0);
        o1 = __builtin_amdgcn_mfma_f32_32x32x8bf16_1k(pf[cc][gg], vf1, o1, 0, 0, 0);
      }
    __builtin_amdgcn_s_setprio(0);

    // rotate bias buffers (SSA-renamed away under unroll 2)
    #pragma unroll
    for (int u = 0; u < 8; u++) bl_cur[u] = bl_nxt[u];
  }

  // full k-half denominator for q-row l32 (partner half-lane has the other half)
  float l2 = l_run + __shfl_xor(l_run, 32);

  // combine the two k-halves through group-1's LDS region (done with its K/V)
  float* sO = (float*)(smem + 18432);   // 128 q x 64 d fp32 = 32KB
  float* sL = sO + 128 * 64;            // 128 floats

  __syncthreads();
  if (g == 1) {
    #pragma unroll
    for (int r = 0; r < 16; r++) {
      int ql = (r & 3) + 8 * (r >> 2) + 4 * hl;
      sO[(wg * 32 + ql) * 64 + l32]      = o0[r];
      sO[(wg * 32 + ql) * 64 + 32 + l32] = o1[r];
    }
    if (hl == 0) sL[wg * 32 + l32] = l2;
  }
  __syncthreads();
  if (g == 0) {
    float linv = __builtin_amdgcn_rcpf(l2 + sL[wg * 32 + l32]);
    #pragma unroll
    for (int r = 0; r < 16; r++) {
      int ql = (r & 3) + 8 * (r >> 2) + 4 * hl;
      float sc = __shfl(linv, ql);
      size_t base = ((size_t)(b * S_ + q0 + ql) * H_ + h) * D_;
      float a0 = o0[r] + sO[(wg * 32 + ql) * 64 + l32];
      float a1 = o1[r] + sO[(wg * 32 + ql) * 64 + 32 + l32];
      Out[base + l32]      = f2bf(a0 * sc);
      Out[base + 32 + l32] = f2bf(a1 * sc);
    }
  }
}

// ---------------- launch ----------------
extern "C" void kernel_launch(void* const* d_in, const int* in_sizes, int n_in,
                              void* d_out, int out_size, void* d_ws, size_t ws_size,
                              hipStream_t stream) {
  (void)in_sizes; (void)n_in; (void)out_size; (void)ws_size;
  const float* x    = (const float*)d_in[0];
  const float* sins = (const float*)d_in[1];
  const float* ab   = (const float*)d_in[2];
  const float* Wq   = (const float*)d_in[3];
  const float* bq   = (const float*)d_in[4];
  const float* Wk   = (const float*)d_in[5];
  const float* bk   = (const float*)d_in[6];
  const float* Wv   = (const float*)d_in[7];
  const float* bv   = (const float*)d_in[8];
  const float* Wo   = (const float*)d_in[9];
  float* out = (float*)d_out;
  char* ws = (char*)d_ws;

  unsigned short* xb  = (unsigned short*)(ws);                       // 8 MB
  unsigned short* Wqt = (unsigned short*)(ws + ((size_t) 8 << 20));  // 2 MB each
  unsigned short* Wkt = (unsigned short*)(ws + ((size_t)10 << 20));
  unsigned short* Wvt = (unsigned short*)(ws + ((size_t)12 << 20));
  unsigned short* Wot = (unsigned short*)(ws + ((size_t)14 << 20));
  unsigned short* Qb  = (unsigned short*)(ws + ((size_t)16 << 20));  // 8 MB
  unsigned short* Kb  = (unsigned short*)(ws + ((size_t)24 << 20));  // 8 MB
  unsigned short* Vtb = (unsigned short*)(ws + ((size_t)32 << 20));  // 8 MB, [b][h][d][s]
  unsigned short* Ab  = (unsigned short*)(ws + ((size_t)40 << 20));  // 8 MB

  const float c1 = 0.125f * 1.44269504088896f;  // 1/sqrt(D) * log2(e), folded into Q

  cast_bf16<<<dim3((M_ * HID_) / (256 * 4)), dim3(256), 0, stream>>>(x, xb);
  transW<<<dim3(32, 32, 4), dim3(32, 8), 0, stream>>>(Wq, Wk, Wv, Wo, Wqt, Wkt, Wvt, Wot);
  gemm_bt<0><<<dim3(8, 32, 3), dim3(256), 0, stream>>>(xb, Wqt, Wkt, Wvt, bq, bk, bv,
                                                       Qb, Kb, Vtb, sins, c1);
  attn<<<dim3(S_ / 128, H_, B_), dim3(512), 0, stream>>>(Qb, Kb, Vtb, ab, Ab);
  gemm_bt64<<<dim3(HID_ / 64, M_ / 128), dim3(256), 0, stream>>>(Ab, Wot, out);
}